// Round 2
// baseline (1130.254 us; speedup 1.0000x reference)
//
#include <hip/hip_runtime.h>
#include <hip/hip_cooperative_groups.h>

namespace cg = cooperative_groups;

#define DIM   1024
#define BATCH 128
#define MAT   (BATCH*DIM)     // 131072
#define NROWS MAT             // one attn row per (b,i)
#define DS    32

// nw-row quota bases (rows written per phase, statically scheduled)
#define QC   16384   // phase C writes rows [0, QC)
#define QD1  22528   // D1 quota: [QC, QD1)      = 3072 waves * 2
#define QD2  29696   // D2 quota: [QD1, QD2)     = 3584 waves * 2
#define QD3  35840
#define QD4  43008
#define QD5  49152
#define QD6  56320   // E: [QD6, 131072)

struct Params {
  const float *x,*Wq,*bq,*Wk,*bk,*Wv,*bv,*Wo,*bo,*W1,*b1,*W2,*b2;
  float *out,*nw;
  float *q,*k,*v,*araw,*x2,*h,*P;
};

// ---------------------------------------------------------------------------
// One split-K partial GEMM tile: P[b][n] += X[b, k0:k0+KC] . W[n0+n, k0:k0+KC]
// tile 128b x 64n, 256 threads, per-thread 8b x 4n. LDS transposed [c][row],
// +4 padding on the row stride (132/68) keeps float4 alignment and cuts the
// 8-way staging-write bank conflict to 4-way.
// ---------------------------------------------------------------------------
__device__ __forceinline__ void gemm_tile(
    const float* __restrict__ X, const float* __restrict__ W,
    float* __restrict__ Pout, int n0, int k0, int KC,
    float* xt, float* wt)
{
  const int tid = threadIdx.x;
  const int tn = tid & 15, tb = tid >> 4;
  const int b_base = tb*8, n_base = tn*4;
  float acc[8][4];
#pragma unroll
  for (int i=0;i<8;++i)
#pragma unroll
    for (int j=0;j<4;++j) acc[i][j]=0.f;

  for (int s=0; s<KC/DS; ++s) {
    const int kk = k0 + s*DS;
#pragma unroll
    for (int r=0;r<4;++r) {
      const int row = (tid>>3) + 32*r;
      const int c0  = (tid&7)*4;
      const float4 vv = *(const float4*)(X + (size_t)row*DIM + kk + c0);
      xt[(c0+0)*132+row]=vv.x; xt[(c0+1)*132+row]=vv.y;
      xt[(c0+2)*132+row]=vv.z; xt[(c0+3)*132+row]=vv.w;
    }
#pragma unroll
    for (int r=0;r<2;++r) {
      const int row = (tid>>3) + 32*r;
      const int c0  = (tid&7)*4;
      const float4 vv = *(const float4*)(W + (size_t)(n0+row)*DIM + kk + c0);
      wt[(c0+0)*68+row]=vv.x; wt[(c0+1)*68+row]=vv.y;
      wt[(c0+2)*68+row]=vv.z; wt[(c0+3)*68+row]=vv.w;
    }
    __syncthreads();
#pragma unroll 4
    for (int d=0; d<DS; ++d) {
      const float4 xa0 = *(const float4*)&xt[d*132 + b_base];
      const float4 xa1 = *(const float4*)&xt[d*132 + b_base + 4];
      const float4 wa  = *(const float4*)&wt[d*68  + n_base];
      const float xr[8] = {xa0.x,xa0.y,xa0.z,xa0.w, xa1.x,xa1.y,xa1.z,xa1.w};
      const float wr[4] = {wa.x,wa.y,wa.z,wa.w};
#pragma unroll
      for (int bb=0;bb<8;++bb)
#pragma unroll
        for (int nn=0;nn<4;++nn) acc[bb][nn] += xr[bb]*wr[nn];
    }
    __syncthreads();
  }
#pragma unroll
  for (int bb=0;bb<8;++bb) {
    const float4 st = make_float4(acc[bb][0],acc[bb][1],acc[bb][2],acc[bb][3]);
    *(float4*)(Pout + (size_t)(b_base+bb)*DIM + n0 + n_base) = st;
  }
}

// ---------------------------------------------------------------------------
// One attention row (one wave): softmax(q[row]*k[b,:]/32) -> optional nw write,
// optional attn_raw (= normalized dot with v). Rank-1 scores: no max pass
// needed (|c*k| < ~0.25). k/v read through L1 (4 KB rows, hot per-b).
// ---------------------------------------------------------------------------
template<bool WRITE, bool AR>
__device__ __forceinline__ void attn_row(const Params& p, int row, int lane)
{
  const int b = row >> 10;
  const float c = p.q[row] * 0.03125f;
  const float4* __restrict__ k4 = (const float4*)(p.k + ((size_t)b<<10));
  const float4* __restrict__ v4 = (const float4*)(p.v + ((size_t)b<<10));
  float sum=0.f, dot=0.f;
  float4 e[4];
#pragma unroll
  for (int t=0;t<4;++t) {
    const float4 kk = k4[lane + 64*t];
    float4 pp;
    pp.x=__expf(c*kk.x); pp.y=__expf(c*kk.y);
    pp.z=__expf(c*kk.z); pp.w=__expf(c*kk.w);
    sum += (pp.x+pp.y)+(pp.z+pp.w);
    if (AR) {
      const float4 vv = v4[lane + 64*t];
      dot += pp.x*vv.x + pp.y*vv.y + pp.z*vv.z + pp.w*vv.w;
    }
    e[t]=pp;
  }
#pragma unroll
  for (int off=32; off>=1; off>>=1) {
    sum += __shfl_xor(sum, off);
    if (AR) dot += __shfl_xor(dot, off);
  }
  const float rinv = 1.f/sum;
  if (WRITE) {
    float4* o = (float4*)(p.nw + ((size_t)row<<10));
#pragma unroll
    for (int t=0;t<4;++t) {
      float4 pp=e[t];
      pp.x*=rinv; pp.y*=rinv; pp.z*=rinv; pp.w*=rinv;
      o[lane + 64*t] = pp;
    }
  }
  if (AR && lane==0) p.araw[row] = dot*rinv;
}

// ---------------------------------------------------------------------------
// Mega-kernel: 1024 blocks x 256 threads, cooperative.
// A: QKV split-8 partials | B: reduce+bias -> q,k,v | C: attn_raw all rows +
// nw rows [0,QC) | D1..D6: Wo/FFN chain on blocks 0..255(128), idle blocks
// write nw quotas | E: remaining nw rows with full grid.
// ---------------------------------------------------------------------------
__global__ __launch_bounds__(256,4) void megakernel(Params p)
{
  __shared__ float xt[DS*132];
  __shared__ float wt[DS*68];
  cg::grid_group grid = cg::this_grid();
  const int bid = blockIdx.x, tid = threadIdx.x;
  const int wave = tid>>6, lane = tid&63;
  const int gwave = bid*4 + wave;

  // ---- A: QKV partial GEMMs (3 mats x 16 ntiles x 8 splits = 384 blocks)
  if (bid < 384) {
    const int z = bid >> 7, rem = bid & 127;
    const int nt = rem >> 3, sp = rem & 7;
    const float* W = (z==0) ? p.Wq : (z==1) ? p.Wk : p.Wv;
    gemm_tile(p.x, W, p.P + (size_t)(z*8+sp)*MAT, nt*64, sp*128, 128, xt, wt);
  }
  grid.sync();

  // ---- B: reduce 8 partials + bias -> q,k,v  (98304 float4 tasks)
  {
    const int t = bid*256 + tid;
    if (t < 3*32768) {
      const int z = t >> 15, idx4 = t & 32767;
      const float4* Pz = (const float4*)(p.P + (size_t)z*8*MAT);
      const float*  bias = (z==0) ? p.bq : (z==1) ? p.bk : p.bv;
      float* outz = (z==0) ? p.q : (z==1) ? p.k : p.v;
      float4 s = Pz[idx4];
#pragma unroll
      for (int sp=1; sp<8; ++sp) {
        const float4 t2 = Pz[sp*(MAT/4)+idx4];
        s.x+=t2.x; s.y+=t2.y; s.z+=t2.z; s.w+=t2.w;
      }
      const float4 b4 = ((const float4*)bias)[idx4 & 255];
      s.x+=b4.x; s.y+=b4.y; s.z+=b4.z; s.w+=b4.w;
      ((float4*)outz)[idx4] = s;
    }
  }
  grid.sync();

  // ---- C: attn_raw for ALL rows (VALU-bound); also write nw rows [0,QC)
  {
    const int base = gwave*32;
    if (gwave < QC/32) {
#pragma unroll 1
      for (int r=0;r<32;++r) attn_row<true ,true>(p, base+r, lane);
    } else {
#pragma unroll 1
      for (int r=0;r<32;++r) attn_row<false,true>(p, base+r, lane);
    }
  }
  grid.sync();

  // ---- D1: Wo GEMM (16 ntiles x 16 splits = 256 blocks) || nw quota
  if (bid < 256) {
    gemm_tile(p.araw, p.Wo, p.P + (size_t)(bid&15)*MAT, (bid>>4)*64, (bid&15)*64, 64, xt, wt);
  } else {
    const int r0 = QC + ((bid-256)*4 + wave)*2;
    attn_row<true,false>(p, r0,   lane);
    attn_row<true,false>(p, r0+1, lane);
  }
  grid.sync();

  // ---- D2: reduce -> x2 = sum + bo + x   || nw quota
  if (bid < 128) {
    const int idx4 = bid*256 + tid;
    const float4* P4 = (const float4*)p.P;
    float4 s = P4[idx4];
#pragma unroll
    for (int sp=1; sp<16; ++sp){ const float4 t2=P4[sp*(MAT/4)+idx4];
      s.x+=t2.x;s.y+=t2.y;s.z+=t2.z;s.w+=t2.w; }
    const float4 b4 = ((const float4*)p.bo)[idx4 & 255];
    const float4 xv = ((const float4*)p.x)[idx4];
    s.x+=b4.x+xv.x; s.y+=b4.y+xv.y; s.z+=b4.z+xv.z; s.w+=b4.w+xv.w;
    ((float4*)p.x2)[idx4] = s;
  } else {
    const int r0 = QD1 + ((bid-128)*4 + wave)*2;
    attn_row<true,false>(p, r0,   lane);
    attn_row<true,false>(p, r0+1, lane);
  }
  grid.sync();

  // ---- D3: FFN1 GEMM || nw quota
  if (bid < 256) {
    gemm_tile(p.x2, p.W1, p.P + (size_t)(bid&15)*MAT, (bid>>4)*64, (bid&15)*64, 64, xt, wt);
  } else {
    const int r0 = QD2 + ((bid-256)*4 + wave)*2;
    attn_row<true,false>(p, r0,   lane);
    attn_row<true,false>(p, r0+1, lane);
  }
  grid.sync();

  // ---- D4: reduce -> h = relu(sum + b1) || nw quota
  if (bid < 128) {
    const int idx4 = bid*256 + tid;
    const float4* P4 = (const float4*)p.P;
    float4 s = P4[idx4];
#pragma unroll
    for (int sp=1; sp<16; ++sp){ const float4 t2=P4[sp*(MAT/4)+idx4];
      s.x+=t2.x;s.y+=t2.y;s.z+=t2.z;s.w+=t2.w; }
    const float4 b4 = ((const float4*)p.b1)[idx4 & 255];
    s.x=fmaxf(s.x+b4.x,0.f); s.y=fmaxf(s.y+b4.y,0.f);
    s.z=fmaxf(s.z+b4.z,0.f); s.w=fmaxf(s.w+b4.w,0.f);
    ((float4*)p.h)[idx4] = s;
  } else {
    const int r0 = QD3 + ((bid-128)*4 + wave)*2;
    attn_row<true,false>(p, r0,   lane);
    attn_row<true,false>(p, r0+1, lane);
  }
  grid.sync();

  // ---- D5: FFN2 GEMM || nw quota
  if (bid < 256) {
    gemm_tile(p.h, p.W2, p.P + (size_t)(bid&15)*MAT, (bid>>4)*64, (bid&15)*64, 64, xt, wt);
  } else {
    const int r0 = QD4 + ((bid-256)*4 + wave)*2;
    attn_row<true,false>(p, r0,   lane);
    attn_row<true,false>(p, r0+1, lane);
  }
  grid.sync();

  // ---- D6: reduce -> out = sum + b2 + x2 || nw quota (no sync needed after)
  if (bid < 128) {
    const int idx4 = bid*256 + tid;
    const float4* P4 = (const float4*)p.P;
    float4 s = P4[idx4];
#pragma unroll
    for (int sp=1; sp<16; ++sp){ const float4 t2=P4[sp*(MAT/4)+idx4];
      s.x+=t2.x;s.y+=t2.y;s.z+=t2.z;s.w+=t2.w; }
    const float4 b4 = ((const float4*)p.b2)[idx4 & 255];
    const float4 xv = ((const float4*)p.x2)[idx4];
    s.x+=b4.x+xv.x; s.y+=b4.y+xv.y; s.z+=b4.z+xv.z; s.w+=b4.w+xv.w;
    ((float4*)p.out)[idx4] = s;
  } else {
    const int r0 = QD5 + ((bid-128)*4 + wave)*2;
    attn_row<true,false>(p, r0,   lane);
    attn_row<true,false>(p, r0+1, lane);
  }

  // ---- E: remaining nw rows, full grid (write-BW-bound)
#pragma unroll 1
  for (int row = QD6 + gwave; row < NROWS; row += 4096)
    attn_row<true,false>(p, row, lane);
}

// ---------------------------------------------------------------------------
// Fallback (round-1 proven path) in case cooperative launch is rejected.
// ---------------------------------------------------------------------------
__global__ __launch_bounds__(256) void fb_gemm_qkv(
    const float* __restrict__ X, const float* __restrict__ W0,
    const float* __restrict__ W1, const float* __restrict__ W2,
    float* __restrict__ P)
{
  __shared__ float xt[DS*132];
  __shared__ float wt[DS*68];
  const int z = blockIdx.z;
  const float* W = (z==0)?W0:(z==1)?W1:W2;
  gemm_tile(X, W, P + (size_t)(z*8+blockIdx.y)*MAT,
            blockIdx.x*64, blockIdx.y*128, 128, xt, wt);
}

__global__ __launch_bounds__(256) void fb_gemm1(
    const float* __restrict__ X, const float* __restrict__ W, float* __restrict__ P)
{
  __shared__ float xt[DS*132];
  __shared__ float wt[DS*68];
  gemm_tile(X, W, P + (size_t)blockIdx.y*MAT,
            blockIdx.x*64, blockIdx.y*64, 64, xt, wt);
}

__global__ __launch_bounds__(256) void fb_reduce(
    const float* __restrict__ P, const float* __restrict__ bias,
    const float* __restrict__ extra, float* __restrict__ out,
    int relu, int nsplit)
{
  const int idx4 = blockIdx.x*256 + threadIdx.x;
  const float4* P4 = (const float4*)P;
  float4 s = P4[idx4];
  for (int sp=1; sp<nsplit; ++sp){ const float4 t2=P4[sp*(MAT/4)+idx4];
    s.x+=t2.x;s.y+=t2.y;s.z+=t2.z;s.w+=t2.w; }
  const float4 b4 = ((const float4*)bias)[idx4 & 255];
  s.x+=b4.x; s.y+=b4.y; s.z+=b4.z; s.w+=b4.w;
  if (relu){ s.x=fmaxf(s.x,0.f);s.y=fmaxf(s.y,0.f);s.z=fmaxf(s.z,0.f);s.w=fmaxf(s.w,0.f); }
  if (extra){ const float4 e=((const float4*)extra)[idx4];
    s.x+=e.x;s.y+=e.y;s.z+=e.z;s.w+=e.w; }
  ((float4*)out)[idx4] = s;
}

__global__ __launch_bounds__(256) void fb_attn(Params p)
{
  const int gw = blockIdx.x*4 + (threadIdx.x>>6);
  const int lane = threadIdx.x & 63;
  const int base = gw*32;
#pragma unroll 1
  for (int r=0;r<32;++r) attn_row<true,true>(p, base+r, lane);
}

// ---------------------------------------------------------------------------
extern "C" void kernel_launch(void* const* d_in, const int* in_sizes, int n_in,
                              void* d_out, int out_size, void* d_ws, size_t ws_size,
                              hipStream_t stream)
{
  (void)in_sizes; (void)n_in; (void)out_size; (void)ws_size;
  Params p;
  p.x  = (const float*)d_in[0];
  p.Wq = (const float*)d_in[1];  p.bq = (const float*)d_in[2];
  p.Wk = (const float*)d_in[3];  p.bk = (const float*)d_in[4];
  p.Wv = (const float*)d_in[5];  p.bv = (const float*)d_in[6];
  p.Wo = (const float*)d_in[7];  p.bo = (const float*)d_in[8];
  p.W1 = (const float*)d_in[9];  p.b1 = (const float*)d_in[10];
  p.W2 = (const float*)d_in[11]; p.b2 = (const float*)d_in[12];
  p.out = (float*)d_out;
  p.nw  = p.out + MAT;
  float* ws = (float*)d_ws;
  p.q = ws;          p.k = ws + MAT;    p.v = ws + 2*MAT;
  p.araw = ws + 3*MAT; p.x2 = ws + 4*MAT; p.h = ws + 5*MAT;
  p.P = ws + 6*MAT;  // 24 * MAT floats (12 MB) — same footprint as round 1

  void* args[] = { &p };
  hipError_t err = hipLaunchCooperativeKernel((const void*)megakernel,
                                              dim3(1024), dim3(256), args, 0, stream);
  if (err != hipSuccess) {
    (void)hipGetLastError();
    // round-1 proven multi-kernel path
    fb_gemm_qkv<<<dim3(16,8,3), 256, 0, stream>>>(p.x, p.Wq, p.Wk, p.Wv, p.P);
    fb_reduce<<<128,256,0,stream>>>(p.P,          p.bq, nullptr, p.q, 0, 8);
    fb_reduce<<<128,256,0,stream>>>(p.P + 8*MAT,  p.bk, nullptr, p.k, 0, 8);
    fb_reduce<<<128,256,0,stream>>>(p.P + 16*MAT, p.bv, nullptr, p.v, 0, 8);
    fb_attn<<<1024,256,0,stream>>>(p);
    fb_gemm1<<<dim3(16,16),256,0,stream>>>(p.araw, p.Wo, p.P);
    fb_reduce<<<128,256,0,stream>>>(p.P, p.bo, p.x,  p.x2, 0, 16);
    fb_gemm1<<<dim3(16,16),256,0,stream>>>(p.x2, p.W1, p.P);
    fb_reduce<<<128,256,0,stream>>>(p.P, p.b1, nullptr, p.h, 1, 16);
    fb_gemm1<<<dim3(16,16),256,0,stream>>>(p.h, p.W2, p.P);
    fb_reduce<<<128,256,0,stream>>>(p.P, p.b2, p.x2, p.out, 0, 16);
  }
}

// Round 3
// 770.665 us; speedup vs baseline: 1.4666x; 1.4666x over previous
//
#include <hip/hip_runtime.h>

#define DIM   1024
#define BATCH 128
#define MAT   (BATCH*DIM)     // 131072
#define NROWS MAT
#define DS    32
#define CHUNK 4

// work-steal caps (rows of nw, cumulative)
#define CAP3 16384
#define CAP4 32768
#define CAP5 49152
#define CAP6 65536

struct Params {
  const float *x,*Wq,*bq,*Wk,*bk,*Wv,*bv,*Wo,*bo,*W1,*b1,*W2,*b2;
  float *out,*nw;
  float *q,*k,*v,*araw,*x2,*h,*P;
};

// ---------------------------------------------------------------------------
// One attention row (one wave): softmax(q[row]*k[b,:]/32) -> optional nw write,
// optional attn_raw. Rank-1 scores: no max pass needed (|c*k| < ~0.3).
// k/v rows (4KB) are L1/L2 hot.
// ---------------------------------------------------------------------------
template<bool WRITE, bool AR>
__device__ __forceinline__ void attn_row(const Params& p, int row, int lane)
{
  const int b = row >> 10;
  const float c = p.q[row] * 0.03125f;
  const float4* __restrict__ k4 = (const float4*)(p.k + ((size_t)b<<10));
  const float4* __restrict__ v4 = (const float4*)(p.v + ((size_t)b<<10));
  float sum=0.f, dot=0.f;
  float4 e[4];
#pragma unroll
  for (int t=0;t<4;++t) {
    const float4 kk = k4[lane + 64*t];
    float4 pp;
    pp.x=__expf(c*kk.x); pp.y=__expf(c*kk.y);
    pp.z=__expf(c*kk.z); pp.w=__expf(c*kk.w);
    sum += (pp.x+pp.y)+(pp.z+pp.w);
    if (AR) {
      const float4 vv = v4[lane + 64*t];
      dot += pp.x*vv.x + pp.y*vv.y + pp.z*vv.z + pp.w*vv.w;
    }
    e[t]=pp;
  }
#pragma unroll
  for (int off=32; off>=1; off>>=1) {
    sum += __shfl_xor(sum, off);
    if (AR) dot += __shfl_xor(dot, off);
  }
  const float rinv = 1.f/sum;
  if (WRITE) {
    float4* o = (float4*)(p.nw + ((size_t)row<<10));
#pragma unroll
    for (int t=0;t<4;++t) {
      float4 pp=e[t];
      pp.x*=rinv; pp.y*=rinv; pp.z*=rinv; pp.w*=rinv;
      o[lane + 64*t] = pp;
    }
  }
  if (AR && lane==0) p.araw[row] = dot*rinv;
}

// Per-wave work-stealing nw writer: rows [base, cap), exactly-once coverage,
// value independent of which wave writes -> deterministic output.
__device__ __forceinline__ void steal_write(const Params& p, int* ctr,
                                            int base, int cap, int lane)
{
  for (;;) {
    int old = 0;
    if (lane == 0) old = atomicAdd(ctr, CHUNK);
    old = __shfl(old, 0);
    const int start = base + old;
    if (start >= cap) return;
    const int end = (start + CHUNK < cap) ? start + CHUNK : cap;
    for (int r = start; r < end; ++r) attn_row<true,false>(p, r, lane);
  }
}

// ---------------------------------------------------------------------------
// QKV split-K partial GEMM (proven round-1 kernel). tile 128b x 64n, KC=128.
// ---------------------------------------------------------------------------
__device__ __forceinline__ void gemm_tile(
    const float* __restrict__ X, const float* __restrict__ W,
    float* __restrict__ Pout, int n0, int k0, int KC,
    float* xt, float* wt)
{
  const int tid = threadIdx.x;
  const int tn = tid & 15, tb = tid >> 4;
  const int b_base = tb*8, n_base = tn*4;
  float acc[8][4];
#pragma unroll
  for (int i=0;i<8;++i)
#pragma unroll
    for (int j=0;j<4;++j) acc[i][j]=0.f;

  for (int s=0; s<KC/DS; ++s) {
    const int kk = k0 + s*DS;
#pragma unroll
    for (int r=0;r<4;++r) {
      const int row = (tid>>3) + 32*r;
      const int c0  = (tid&7)*4;
      const float4 vv = *(const float4*)(X + (size_t)row*DIM + kk + c0);
      xt[(c0+0)*132+row]=vv.x; xt[(c0+1)*132+row]=vv.y;
      xt[(c0+2)*132+row]=vv.z; xt[(c0+3)*132+row]=vv.w;
    }
#pragma unroll
    for (int r=0;r<2;++r) {
      const int row = (tid>>3) + 32*r;
      const int c0  = (tid&7)*4;
      const float4 vv = *(const float4*)(W + (size_t)(n0+row)*DIM + kk + c0);
      wt[(c0+0)*68+row]=vv.x; wt[(c0+1)*68+row]=vv.y;
      wt[(c0+2)*68+row]=vv.z; wt[(c0+3)*68+row]=vv.w;
    }
    __syncthreads();
#pragma unroll 4
    for (int d=0; d<DS; ++d) {
      const float4 xa0 = *(const float4*)&xt[d*132 + b_base];
      const float4 xa1 = *(const float4*)&xt[d*132 + b_base + 4];
      const float4 wa  = *(const float4*)&wt[d*68  + n_base];
      const float xr[8] = {xa0.x,xa0.y,xa0.z,xa0.w, xa1.x,xa1.y,xa1.z,xa1.w};
      const float wr[4] = {wa.x,wa.y,wa.z,wa.w};
#pragma unroll
      for (int bb=0;bb<8;++bb)
#pragma unroll
        for (int nn=0;nn<4;++nn) acc[bb][nn] += xr[bb]*wr[nn];
    }
    __syncthreads();
  }
#pragma unroll
  for (int bb=0;bb<8;++bb) {
    const float4 st = make_float4(acc[bb][0],acc[bb][1],acc[bb][2],acc[bb][3]);
    *(float4*)(Pout + (size_t)(b_base+bb)*DIM + n0 + n_base) = st;
  }
}

__global__ __launch_bounds__(256) void qkv_partial(
    const float* __restrict__ X, const float* __restrict__ W0,
    const float* __restrict__ W1, const float* __restrict__ W2,
    float* __restrict__ P)
{
  __shared__ float xt[DS*132];
  __shared__ float wt[DS*68];
  const int z = blockIdx.z;
  const float* W = (z==0)?W0:(z==1)?W1:W2;
  gemm_tile(X, W, P + (size_t)(z*8+blockIdx.y)*MAT,
            blockIdx.x*64, blockIdx.y*128, 128, xt, wt);
}

// 384 blocks: reduce 8 partials + bias for q,k,v in one dispatch
__global__ __launch_bounds__(256) void qkv_reduce(Params p)
{
  const int t = blockIdx.x*256 + threadIdx.x;     // 0..98303
  const int z = t >> 15, idx4 = t & 32767;
  const float4* Pz = (const float4*)(p.P + (size_t)z*8*MAT);
  const float*  bias = (z==0) ? p.bq : (z==1) ? p.bk : p.bv;
  float* outz = (z==0) ? p.q : (z==1) ? p.k : p.v;
  float4 s = Pz[idx4];
#pragma unroll
  for (int sp=1; sp<8; ++sp) {
    const float4 t2 = Pz[sp*(MAT/4)+idx4];
    s.x+=t2.x; s.y+=t2.y; s.z+=t2.z; s.w+=t2.w;
  }
  const float4 b4 = ((const float4*)bias)[idx4 & 255];
  s.x+=b4.x; s.y+=b4.y; s.z+=b4.z; s.w+=b4.w;
  ((float4*)outz)[idx4] = s;
}

// ---------------------------------------------------------------------------
// attn_raw for all rows (768 blocks, VALU-bound) || nw writers (256 blocks)
// ---------------------------------------------------------------------------
__global__ __launch_bounds__(256,4) void attn_steal(Params p, int* ctr,
                                                    int base, int cap)
{
  const int bid = blockIdx.x, tid = threadIdx.x;
  const int wave = tid>>6, lane = tid&63;
  if (bid < 768) {
    const int gw = bid*4 + wave;        // 0..3071, 43 rows each
    int r0 = gw*43, r1 = r0 + 43;
    if (r1 > NROWS) r1 = NROWS;
#pragma unroll 1
    for (int r = r0; r < r1; ++r) attn_row<false,true>(p, r, lane);
  } else {
    steal_write(p, ctr, base, cap, lane);
  }
}

// ---------------------------------------------------------------------------
// Deep-K GEMM (tile 128b x 16n, K=1024, fused epilogue) on blocks 0..63;
// blocks 64..1023 work-steal nw rows. out = [relu](X@W^T + bias) [+ extra]
// ---------------------------------------------------------------------------
__global__ __launch_bounds__(256,4) void chain_gemm(Params p,
    const float* __restrict__ X, const float* __restrict__ W,
    const float* __restrict__ bias, const float* __restrict__ extra,
    float* __restrict__ out, int relu, int* ctr, int base, int cap)
{
  __shared__ float xt[DS*132];
  __shared__ float wt[DS*20];
  const int tid = threadIdx.x, lane = tid&63;
  if (blockIdx.x >= 64) { steal_write(p, ctr, base, cap, lane); return; }

  const int n0 = blockIdx.x * 16;
  const int tb = tid>>2, tn = tid&3;     // 64 b-groups x 4 n-groups
  float acc[2][4] = {{0.f,0.f,0.f,0.f},{0.f,0.f,0.f,0.f}};

  for (int kk=0; kk<DIM; kk+=DS) {
#pragma unroll
    for (int r=0;r<4;++r) {
      const int row = (tid>>3) + 32*r;
      const int c0  = (tid&7)*4;
      const float4 vv = *(const float4*)(X + (size_t)row*DIM + kk + c0);
      xt[(c0+0)*132+row]=vv.x; xt[(c0+1)*132+row]=vv.y;
      xt[(c0+2)*132+row]=vv.z; xt[(c0+3)*132+row]=vv.w;
    }
    if (tid < 128) {
      const int row = tid>>3;            // 0..15
      const int c0  = (tid&7)*4;
      const float4 vv = *(const float4*)(W + (size_t)(n0+row)*DIM + kk + c0);
      wt[(c0+0)*20+row]=vv.x; wt[(c0+1)*20+row]=vv.y;
      wt[(c0+2)*20+row]=vv.z; wt[(c0+3)*20+row]=vv.w;
    }
    __syncthreads();
#pragma unroll 8
    for (int d=0; d<DS; ++d) {
      const float2 xa = *(const float2*)&xt[d*132 + tb*2];
      const float4 wa = *(const float4*)&wt[d*20  + tn*4];
      acc[0][0]+=xa.x*wa.x; acc[0][1]+=xa.x*wa.y;
      acc[0][2]+=xa.x*wa.z; acc[0][3]+=xa.x*wa.w;
      acc[1][0]+=xa.y*wa.x; acc[1][1]+=xa.y*wa.y;
      acc[1][2]+=xa.y*wa.z; acc[1][3]+=xa.y*wa.w;
    }
    __syncthreads();
  }

  const float4 b4 = *(const float4*)(bias + n0 + tn*4);
#pragma unroll
  for (int i=0;i<2;++i) {
    const int b = tb*2 + i;
    float4 s = make_float4(acc[i][0]+b4.x, acc[i][1]+b4.y,
                           acc[i][2]+b4.z, acc[i][3]+b4.w);
    if (relu) { s.x=fmaxf(s.x,0.f); s.y=fmaxf(s.y,0.f);
                s.z=fmaxf(s.z,0.f); s.w=fmaxf(s.w,0.f); }
    if (extra) {
      const float4 e = *(const float4*)(extra + (size_t)b*DIM + n0 + tn*4);
      s.x+=e.x; s.y+=e.y; s.z+=e.z; s.w+=e.w;
    }
    *(float4*)(out + (size_t)b*DIM + n0 + tn*4) = s;
  }
}

// final mop-up: whole grid writes remaining nw rows
__global__ __launch_bounds__(256,4) void mopup(Params p, int* ctr,
                                               int base, int cap)
{
  steal_write(p, ctr, base, cap, threadIdx.x & 63);
}

// ---------------------------------------------------------------------------
extern "C" void kernel_launch(void* const* d_in, const int* in_sizes, int n_in,
                              void* d_out, int out_size, void* d_ws, size_t ws_size,
                              hipStream_t stream)
{
  (void)in_sizes; (void)n_in; (void)out_size; (void)ws_size;
  Params p;
  p.x  = (const float*)d_in[0];
  p.Wq = (const float*)d_in[1];  p.bq = (const float*)d_in[2];
  p.Wk = (const float*)d_in[3];  p.bk = (const float*)d_in[4];
  p.Wv = (const float*)d_in[5];  p.bv = (const float*)d_in[6];
  p.Wo = (const float*)d_in[7];  p.bo = (const float*)d_in[8];
  p.W1 = (const float*)d_in[9];  p.b1 = (const float*)d_in[10];
  p.W2 = (const float*)d_in[11]; p.b2 = (const float*)d_in[12];
  p.out = (float*)d_out;
  p.nw  = p.out + MAT;
  float* ws = (float*)d_ws;
  p.q = ws;            p.k  = ws + MAT;   p.v = ws + 2*MAT;
  p.araw = ws + 3*MAT; p.x2 = ws + 4*MAT; p.h = ws + 5*MAT;
  p.P = ws + 6*MAT;    // 24*MAT floats; free after qkv_reduce

  // Work-steal counters live in the (then-free) P region; one 64-int cache
  // line apart. Zeroed by a memset node AFTER qkv_reduce consumed P.
  int* ctrs = (int*)p.P;

  qkv_partial<<<dim3(16,8,3), 256, 0, stream>>>(p.x, p.Wq, p.Wk, p.Wv, p.P);
  qkv_reduce<<<384, 256, 0, stream>>>(p);
  hipMemsetAsync(ctrs, 0, 5*64*sizeof(int), stream);

  attn_steal<<<1024, 256, 0, stream>>>(p, ctrs + 0*64, 0,    CAP3);
  chain_gemm<<<1024, 256, 0, stream>>>(p, p.araw, p.Wo, p.bo, p.x,  p.x2, 0,
                                       ctrs + 1*64, CAP3, CAP4);
  chain_gemm<<<1024, 256, 0, stream>>>(p, p.x2,  p.W1, p.b1, nullptr, p.h, 1,
                                       ctrs + 2*64, CAP4, CAP5);
  chain_gemm<<<1024, 256, 0, stream>>>(p, p.h,   p.W2, p.b2, p.x2, p.out, 0,
                                       ctrs + 3*64, CAP5, CAP6);
  mopup<<<1024, 256, 0, stream>>>(p, ctrs + 4*64, CAP6, NROWS);
}

// Round 4
// 195.339 us; speedup vs baseline: 5.7861x; 3.9453x over previous
//
#include <hip/hip_runtime.h>

#define DIM   1024
#define BATCH 128
#define MAT   (BATCH*DIM)     // 131072
#define NROWS MAT
#define DS    32

// static nw-row quota bases (cumulative; all partitions are exact)
#define Q1W   10240   // attn dispatch: writer blocks, 1024 waves x 10
#define Q1    16384   // attn dispatch: AR blocks post-quota, 3072 waves x 2
#define A_WO  16384   // chainA Wo:  3072 waves x 6  -> [16384,34816)
#define B_WO  34816   // chainB Wo:  3584 waves x 2  -> [34816,41984)
#define A_W1  41984
#define B_W1  60416
#define A_W2  67584
#define B_W2  86016
#define MBASE 93184   // mopup: [93184,131072) = 37888 rows, 4096 waves

struct Params {
  const float *x,*Wq,*bq,*Wk,*bk,*Wv,*bv,*Wo,*bo,*W1,*b1,*W2,*b2;
  float *out,*nw;
  float *q,*k,*v,*araw,*x2,*h,*P;
};

// ---------------------------------------------------------------------------
// One attention row (one wave): softmax(q[row]*k[b,:]/32) -> optional nw write,
// optional attn_raw. Rank-1 scores: no max pass needed (|c*k| < ~0.3).
// k/v rows (4KB) are L1/L2 hot. Deterministic per row -> any wave may write it.
// ---------------------------------------------------------------------------
template<bool WRITE, bool AR>
__device__ __forceinline__ void attn_row(const Params& p, int row, int lane)
{
  const int b = row >> 10;
  const float c = p.q[row] * 0.03125f;
  const float4* __restrict__ k4 = (const float4*)(p.k + ((size_t)b<<10));
  const float4* __restrict__ v4 = (const float4*)(p.v + ((size_t)b<<10));
  float sum=0.f, dot=0.f;
  float4 e[4];
#pragma unroll
  for (int t=0;t<4;++t) {
    const float4 kk = k4[lane + 64*t];
    float4 pp;
    pp.x=__expf(c*kk.x); pp.y=__expf(c*kk.y);
    pp.z=__expf(c*kk.z); pp.w=__expf(c*kk.w);
    sum += (pp.x+pp.y)+(pp.z+pp.w);
    if (AR) {
      const float4 vv = v4[lane + 64*t];
      dot += pp.x*vv.x + pp.y*vv.y + pp.z*vv.z + pp.w*vv.w;
    }
    e[t]=pp;
  }
#pragma unroll
  for (int off=32; off>=1; off>>=1) {
    sum += __shfl_xor(sum, off);
    if (AR) dot += __shfl_xor(dot, off);
  }
  const float rinv = 1.f/sum;
  if (WRITE) {
    float4* o = (float4*)(p.nw + ((size_t)row<<10));
#pragma unroll
    for (int t=0;t<4;++t) {
      float4 pp=e[t];
      pp.x*=rinv; pp.y*=rinv; pp.z*=rinv; pp.w*=rinv;
      o[lane + 64*t] = pp;
    }
  }
  if (AR && lane==0) p.araw[row] = dot*rinv;
}

__device__ __forceinline__ void write_rows(const Params& p, int r0, int n, int lane)
{
#pragma unroll 1
  for (int r = r0; r < r0 + n; ++r) attn_row<true,false>(p, r, lane);
}

// ---------------------------------------------------------------------------
// Split-K partial GEMM tile (proven R1 kernel): tile 128b x 64n, 256 threads.
// P[b][n] = X[b, k0:k0+KC] . W[n0+n, k0:k0+KC]. LDS transposed, padded.
// ---------------------------------------------------------------------------
__device__ __forceinline__ void gemm_tile(
    const float* __restrict__ X, const float* __restrict__ W,
    float* __restrict__ Pout, int n0, int k0, int KC,
    float* xt, float* wt)
{
  const int tid = threadIdx.x;
  const int tn = tid & 15, tb = tid >> 4;
  const int b_base = tb*8, n_base = tn*4;
  float acc[8][4];
#pragma unroll
  for (int i=0;i<8;++i)
#pragma unroll
    for (int j=0;j<4;++j) acc[i][j]=0.f;

  for (int s=0; s<KC/DS; ++s) {
    const int kk = k0 + s*DS;
#pragma unroll
    for (int r=0;r<4;++r) {
      const int row = (tid>>3) + 32*r;
      const int c0  = (tid&7)*4;
      const float4 vv = *(const float4*)(X + (size_t)row*DIM + kk + c0);
      xt[(c0+0)*132+row]=vv.x; xt[(c0+1)*132+row]=vv.y;
      xt[(c0+2)*132+row]=vv.z; xt[(c0+3)*132+row]=vv.w;
    }
#pragma unroll
    for (int r=0;r<2;++r) {
      const int row = (tid>>3) + 32*r;
      const int c0  = (tid&7)*4;
      const float4 vv = *(const float4*)(W + (size_t)(n0+row)*DIM + kk + c0);
      wt[(c0+0)*68+row]=vv.x; wt[(c0+1)*68+row]=vv.y;
      wt[(c0+2)*68+row]=vv.z; wt[(c0+3)*68+row]=vv.w;
    }
    __syncthreads();
#pragma unroll 4
    for (int d=0; d<DS; ++d) {
      const float4 xa0 = *(const float4*)&xt[d*132 + b_base];
      const float4 xa1 = *(const float4*)&xt[d*132 + b_base + 4];
      const float4 wa  = *(const float4*)&wt[d*68  + n_base];
      const float xr[8] = {xa0.x,xa0.y,xa0.z,xa0.w, xa1.x,xa1.y,xa1.z,xa1.w};
      const float wr[4] = {wa.x,wa.y,wa.z,wa.w};
#pragma unroll
      for (int bb=0;bb<8;++bb)
#pragma unroll
        for (int nn=0;nn<4;++nn) acc[bb][nn] += xr[bb]*wr[nn];
    }
    __syncthreads();
  }
#pragma unroll
  for (int bb=0;bb<8;++bb) {
    const float4 st = make_float4(acc[bb][0],acc[bb][1],acc[bb][2],acc[bb][3]);
    *(float4*)(Pout + (size_t)(b_base+bb)*DIM + n0 + n_base) = st;
  }
}

// ---------------------------------------------------------------------------
// QKV: 384 blocks of split-8 partials (K=128 each), then 384-block reduce.
// ---------------------------------------------------------------------------
__global__ __launch_bounds__(256) void qkv_partial(
    const float* __restrict__ X, const float* __restrict__ W0,
    const float* __restrict__ W1, const float* __restrict__ W2,
    float* __restrict__ P)
{
  __shared__ float xt[DS*132];
  __shared__ float wt[DS*68];
  const int z = blockIdx.z;
  const float* W = (z==0)?W0:(z==1)?W1:W2;
  gemm_tile(X, W, P + (size_t)(z*8+blockIdx.y)*MAT,
            blockIdx.x*64, blockIdx.y*128, 128, xt, wt);
}

__global__ __launch_bounds__(256) void qkv_reduce(Params p)
{
  const int t = blockIdx.x*256 + threadIdx.x;     // 0..98303
  const int z = t >> 15, idx4 = t & 32767;
  const float4* Pz = (const float4*)(p.P + (size_t)z*8*MAT);
  const float*  bias = (z==0) ? p.bq : (z==1) ? p.bk : p.bv;
  float* outz = (z==0) ? p.q : (z==1) ? p.k : p.v;
  float4 s = Pz[idx4];
#pragma unroll
  for (int sp=1; sp<8; ++sp) {
    const float4 t2 = Pz[sp*(MAT/4)+idx4];
    s.x+=t2.x; s.y+=t2.y; s.z+=t2.z; s.w+=t2.w;
  }
  const float4 b4 = ((const float4*)bias)[idx4 & 255];
  s.x+=b4.x; s.y+=b4.y; s.z+=b4.z; s.w+=b4.w;
  ((float4*)outz)[idx4] = s;
}

// ---------------------------------------------------------------------------
// attn dispatch: blocks 0..767 compute attn_raw for all 131072 rows (43/wave)
// then write 2 nw rows each [Q1W,Q1); blocks 768..1023 write 10 rows each
// [0,Q1W). All static, no atomics.
// ---------------------------------------------------------------------------
__global__ __launch_bounds__(256,4) void attn_mixed(Params p)
{
  const int bid = blockIdx.x, tid = threadIdx.x;
  const int wave = tid>>6, lane = tid&63;
  if (bid < 768) {
    const int gw = bid*4 + wave;          // 0..3071
    int r0 = gw*43, r1 = r0 + 43;
    if (r1 > NROWS) r1 = NROWS;
#pragma unroll 1
    for (int r = r0; r < r1; ++r) attn_row<false,true>(p, r, lane);
    write_rows(p, Q1W + gw*2, 2, lane);
  } else {
    const int gw2 = (bid-768)*4 + wave;   // 0..1023
    write_rows(p, gw2*10, 10, lane);
  }
}

// ---------------------------------------------------------------------------
// chainA: blocks 0..255 = split-16 GEMM partials (K=64); 256..1023 = writers
// (3072 waves x 6 rows from wbase).
// ---------------------------------------------------------------------------
__global__ __launch_bounds__(256,4) void chainA(Params p,
    const float* __restrict__ X, const float* __restrict__ W, int wbase)
{
  __shared__ float xt[DS*132];
  __shared__ float wt[DS*68];
  const int bid = blockIdx.x, tid = threadIdx.x;
  const int wave = tid>>6, lane = tid&63;
  if (bid < 256) {
    gemm_tile(X, W, p.P + (size_t)(bid&15)*MAT, (bid>>4)*64, (bid&15)*64, 64, xt, wt);
  } else {
    const int gw = (bid-256)*4 + wave;    // 0..3071
    write_rows(p, wbase + gw*6, 6, lane);
  }
}

// ---------------------------------------------------------------------------
// chainB: blocks 0..127 = reduce 16 partials + bias [+relu] [+extra];
// 128..1023 = writers (3584 waves x 2 rows from wbase).
// ---------------------------------------------------------------------------
__global__ __launch_bounds__(256,4) void chainB(Params p,
    const float* __restrict__ bias, const float* __restrict__ extra,
    float* __restrict__ out, int relu, int wbase)
{
  const int bid = blockIdx.x, tid = threadIdx.x;
  const int wave = tid>>6, lane = tid&63;
  if (bid < 128) {
    const int idx4 = bid*256 + tid;
    const float4* P4 = (const float4*)p.P;
    float4 s = P4[idx4];
#pragma unroll
    for (int sp=1; sp<16; ++sp) {
      const float4 t2 = P4[sp*(MAT/4)+idx4];
      s.x+=t2.x; s.y+=t2.y; s.z+=t2.z; s.w+=t2.w;
    }
    const float4 b4 = ((const float4*)bias)[idx4 & 255];
    s.x+=b4.x; s.y+=b4.y; s.z+=b4.z; s.w+=b4.w;
    if (relu) { s.x=fmaxf(s.x,0.f); s.y=fmaxf(s.y,0.f);
                s.z=fmaxf(s.z,0.f); s.w=fmaxf(s.w,0.f); }
    if (extra) {
      const float4 e = ((const float4*)extra)[idx4];
      s.x+=e.x; s.y+=e.y; s.z+=e.z; s.w+=e.w;
    }
    ((float4*)out)[idx4] = s;
  } else {
    const int gw = (bid-128)*4 + wave;    // 0..3583
    write_rows(p, wbase + gw*2, 2, lane);
  }
}

// mopup: full grid, stride loop over remaining rows
__global__ __launch_bounds__(256,4) void mopup(Params p)
{
  const int gw = blockIdx.x*4 + (threadIdx.x>>6);  // 0..4095
  const int lane = threadIdx.x & 63;
#pragma unroll 1
  for (int row = MBASE + gw; row < NROWS; row += 4096)
    attn_row<true,false>(p, row, lane);
}

// ---------------------------------------------------------------------------
extern "C" void kernel_launch(void* const* d_in, const int* in_sizes, int n_in,
                              void* d_out, int out_size, void* d_ws, size_t ws_size,
                              hipStream_t stream)
{
  (void)in_sizes; (void)n_in; (void)out_size; (void)ws_size;
  Params p;
  p.x  = (const float*)d_in[0];
  p.Wq = (const float*)d_in[1];  p.bq = (const float*)d_in[2];
  p.Wk = (const float*)d_in[3];  p.bk = (const float*)d_in[4];
  p.Wv = (const float*)d_in[5];  p.bv = (const float*)d_in[6];
  p.Wo = (const float*)d_in[7];  p.bo = (const float*)d_in[8];
  p.W1 = (const float*)d_in[9];  p.b1 = (const float*)d_in[10];
  p.W2 = (const float*)d_in[11]; p.b2 = (const float*)d_in[12];
  p.out = (float*)d_out;
  p.nw  = p.out + MAT;
  float* ws = (float*)d_ws;
  p.q    = ws;         p.k  = ws + MAT;   p.v = ws + 2*MAT;
  p.araw = ws + 3*MAT; p.x2 = ws + 4*MAT; p.h = ws + 5*MAT;
  p.P    = ws + 6*MAT;   // 24*MAT floats for QKV partials; 16*MAT for chain

  qkv_partial<<<dim3(16,8,3), 256, 0, stream>>>(p.x, p.Wq, p.Wk, p.Wv, p.P);
  qkv_reduce<<<384, 256, 0, stream>>>(p);

  attn_mixed<<<1024, 256, 0, stream>>>(p);

  chainA<<<1024, 256, 0, stream>>>(p, p.araw, p.Wo, A_WO);
  chainB<<<1024, 256, 0, stream>>>(p, p.bo, p.x, p.x2, 0, B_WO);

  chainA<<<1024, 256, 0, stream>>>(p, p.x2, p.W1, A_W1);
  chainB<<<1024, 256, 0, stream>>>(p, p.b1, nullptr, p.h, 1, B_W1);

  chainA<<<1024, 256, 0, stream>>>(p, p.h, p.W2, A_W2);
  chainB<<<1024, 256, 0, stream>>>(p, p.b2, p.x2, p.out, 0, B_W2);

  mopup<<<1024, 256, 0, stream>>>(p);
}

// Round 6
// 178.172 us; speedup vs baseline: 6.3436x; 1.0964x over previous
//
#include <hip/hip_runtime.h>

#define DIM   1024
#define BATCH 128
#define MAT   (BATCH*DIM)     // 131072
#define NROWS MAT
#define DS    32

typedef float f4n __attribute__((ext_vector_type(4)));  // native vec for nt builtins

// static nw-row quota bases (cumulative, exact partitions, no atomics)
#define Q_AT  28672            // attn dispatch writers: 1024 waves x 28
#define A_WO  28672            // chainA Wo: 3072 waves x 6 -> [28672,47104)
#define B_WO  47104            // chainB:    3584 waves x 2 -> [47104,54272)
#define A_W1  54272
#define B_W1  72704
#define A_W2  79872
#define B_W2  98304
#define MBASE 105472           // mopup: 25600 rows (1024 waves x7 + 3072 x6)

struct Params {
  const float *x,*Wq,*bq,*Wk,*bk,*Wv,*bv,*Wo,*bo,*W1,*b1,*W2,*b2;
  float *out,*nw;
  float *q,*k,*v,*araw,*x2,*h,*P;
};

// ---------------------------------------------------------------------------
// attn rows with k/v rows held in registers (16 VGPR each), reloaded only on
// batch change. nw stores are nontemporal (write-once data; keep L2 for k/W).
// Rank-1 scores: no max pass needed (|c*k| < ~0.3, exact softmax match).
// ---------------------------------------------------------------------------
template<bool WRITE, bool AR>
__device__ __forceinline__ void attn_range(const Params& p, int r0, int r1, int lane)
{
  int bcur = -1;
  float4 kr[4], vr[4];
#pragma unroll 1
  for (int row = r0; row < r1; ++row) {
    const int b = row >> 10;
    if (b != bcur) {
      bcur = b;
      const float4* __restrict__ k4 = (const float4*)(p.k + ((size_t)b<<10));
#pragma unroll
      for (int t=0;t<4;++t) kr[t] = k4[lane + 64*t];
      if (AR) {
        const float4* __restrict__ v4 = (const float4*)(p.v + ((size_t)b<<10));
#pragma unroll
        for (int t=0;t<4;++t) vr[t] = v4[lane + 64*t];
      }
    }
    const float c = p.q[row] * 0.03125f;
    float sum=0.f, dot=0.f;
    float4 e[4];
#pragma unroll
    for (int t=0;t<4;++t) {
      const float4 kk = kr[t];
      float4 pp;
      pp.x=__expf(c*kk.x); pp.y=__expf(c*kk.y);
      pp.z=__expf(c*kk.z); pp.w=__expf(c*kk.w);
      sum += (pp.x+pp.y)+(pp.z+pp.w);
      if (AR) {
        const float4 vv = vr[t];
        dot += pp.x*vv.x + pp.y*vv.y + pp.z*vv.z + pp.w*vv.w;
      }
      e[t]=pp;
    }
#pragma unroll
    for (int off=32; off>=1; off>>=1) {
      sum += __shfl_xor(sum, off);
      if (AR) dot += __shfl_xor(dot, off);
    }
    const float rinv = 1.f/sum;
    if (WRITE) {
      f4n* o = (f4n*)(p.nw + ((size_t)row<<10));
#pragma unroll
      for (int t=0;t<4;++t) {
        const float4 pp=e[t];
        f4n st;
        st.x = pp.x*rinv; st.y = pp.y*rinv;
        st.z = pp.z*rinv; st.w = pp.w*rinv;
        __builtin_nontemporal_store(st, &o[lane + 64*t]);
      }
    }
    if (AR && lane==0) p.araw[row] = dot*rinv;
  }
}

// ---------------------------------------------------------------------------
// Split-K partial GEMM tile: tile 128b x 64n, 256 threads, KC in steps of 32.
// W loads nontemporal (each W element read once). LDS transposed + padded.
// ---------------------------------------------------------------------------
__device__ __forceinline__ void gemm_tile(
    const float* __restrict__ X, const float* __restrict__ W,
    float* __restrict__ Pout, int n0, int k0, int KC,
    float* xt, float* wt)
{
  const int tid = threadIdx.x;
  const int tn = tid & 15, tb = tid >> 4;
  const int b_base = tb*8, n_base = tn*4;
  float acc[8][4];
#pragma unroll
  for (int i=0;i<8;++i)
#pragma unroll
    for (int j=0;j<4;++j) acc[i][j]=0.f;

  for (int s=0; s<KC/DS; ++s) {
    const int kk = k0 + s*DS;
#pragma unroll
    for (int r=0;r<4;++r) {
      const int row = (tid>>3) + 32*r;
      const int c0  = (tid&7)*4;
      const float4 vv = *(const float4*)(X + (size_t)row*DIM + kk + c0);
      xt[(c0+0)*132+row]=vv.x; xt[(c0+1)*132+row]=vv.y;
      xt[(c0+2)*132+row]=vv.z; xt[(c0+3)*132+row]=vv.w;
    }
#pragma unroll
    for (int r=0;r<2;++r) {
      const int row = (tid>>3) + 32*r;
      const int c0  = (tid&7)*4;
      const f4n vv = __builtin_nontemporal_load(
          (const f4n*)(W + (size_t)(n0+row)*DIM + kk + c0));
      wt[(c0+0)*68+row]=vv.x; wt[(c0+1)*68+row]=vv.y;
      wt[(c0+2)*68+row]=vv.z; wt[(c0+3)*68+row]=vv.w;
    }
    __syncthreads();
#pragma unroll 4
    for (int d=0; d<DS; ++d) {
      const float4 xa0 = *(const float4*)&xt[d*132 + b_base];
      const float4 xa1 = *(const float4*)&xt[d*132 + b_base + 4];
      const float4 wa  = *(const float4*)&wt[d*68  + n_base];
      const float xr[8] = {xa0.x,xa0.y,xa0.z,xa0.w, xa1.x,xa1.y,xa1.z,xa1.w};
      const float wr[4] = {wa.x,wa.y,wa.z,wa.w};
#pragma unroll
      for (int bb=0;bb<8;++bb)
#pragma unroll
        for (int nn=0;nn<4;++nn) acc[bb][nn] += xr[bb]*wr[nn];
    }
    __syncthreads();
  }
#pragma unroll
  for (int bb=0;bb<8;++bb) {
    const float4 st = make_float4(acc[bb][0],acc[bb][1],acc[bb][2],acc[bb][3]);
    *(float4*)(Pout + (size_t)(b_base+bb)*DIM + n0 + n_base) = st;
  }
}

// ---------------------------------------------------------------------------
__global__ __launch_bounds__(256) void qkv_partial(
    const float* __restrict__ X, const float* __restrict__ W0,
    const float* __restrict__ W1, const float* __restrict__ W2,
    float* __restrict__ P)
{
  __shared__ float xt[DS*132];
  __shared__ float wt[DS*68];
  const int z = blockIdx.z;
  const float* W = (z==0)?W0:(z==1)?W1:W2;
  gemm_tile(X, W, P + (size_t)(z*8+blockIdx.y)*MAT,
            blockIdx.x*64, blockIdx.y*128, 128, xt, wt);
}

__global__ __launch_bounds__(256) void qkv_reduce(Params p)
{
  const int t = blockIdx.x*256 + threadIdx.x;     // 0..98303
  const int z = t >> 15, idx4 = t & 32767;
  const float4* Pz = (const float4*)(p.P + (size_t)z*8*MAT);
  const float*  bias = (z==0) ? p.bq : (z==1) ? p.bk : p.bv;
  float* outz = (z==0) ? p.q : (z==1) ? p.k : p.v;
  float4 s = Pz[idx4];
#pragma unroll
  for (int sp=1; sp<8; ++sp) {
    const float4 t2 = Pz[sp*(MAT/4)+idx4];
    s.x+=t2.x; s.y+=t2.y; s.z+=t2.z; s.w+=t2.w;
  }
  const float4 b4 = ((const float4*)bias)[idx4 & 255];
  s.x+=b4.x; s.y+=b4.y; s.z+=b4.z; s.w+=b4.w;
  ((float4*)outz)[idx4] = s;
}

// ---------------------------------------------------------------------------
// attn: blocks 0..767 compute attn_raw for all rows (43/wave, AR only);
// blocks 768..1023 write nw rows [0, Q_AT) (28/wave).
// ---------------------------------------------------------------------------
__global__ __launch_bounds__(256,4) void attn_mixed(Params p)
{
  const int bid = blockIdx.x, tid = threadIdx.x;
  const int wave = tid>>6, lane = tid&63;
  if (bid < 768) {
    const int gw = bid*4 + wave;          // 0..3071
    int r0 = gw*43, r1 = r0 + 43;
    if (r1 > NROWS) r1 = NROWS;
    attn_range<false,true>(p, r0, r1, lane);
  } else {
    const int gw2 = (bid-768)*4 + wave;   // 0..1023
    attn_range<true,false>(p, gw2*28, gw2*28 + 28, lane);
  }
}

// ---------------------------------------------------------------------------
// chainA: blocks 0..255 = split-16 GEMM partials (K=64); 256..1023 = writers
// (3072 waves x 6 rows). chainB: 0..127 = reduce+epilogue; 128..1023 writers
// (3584 waves x 2 rows).
// ---------------------------------------------------------------------------
__global__ __launch_bounds__(256,4) void chainA(Params p,
    const float* __restrict__ X, const float* __restrict__ W, int wbase)
{
  __shared__ float xt[DS*132];
  __shared__ float wt[DS*68];
  const int bid = blockIdx.x, tid = threadIdx.x;
  const int wave = tid>>6, lane = tid&63;
  if (bid < 256) {
    gemm_tile(X, W, p.P + (size_t)(bid&15)*MAT, (bid>>4)*64, (bid&15)*64, 64, xt, wt);
  } else {
    const int gw = (bid-256)*4 + wave;    // 0..3071
    attn_range<true,false>(p, wbase + gw*6, wbase + gw*6 + 6, lane);
  }
}

__global__ __launch_bounds__(256,4) void chainB(Params p,
    const float* __restrict__ bias, const float* __restrict__ extra,
    float* __restrict__ out, int relu, int wbase)
{
  const int bid = blockIdx.x, tid = threadIdx.x;
  const int wave = tid>>6, lane = tid&63;
  if (bid < 128) {
    const int idx4 = bid*256 + tid;
    const float4* P4 = (const float4*)p.P;
    float4 s = P4[idx4];
#pragma unroll
    for (int sp=1; sp<16; ++sp) {
      const float4 t2 = P4[sp*(MAT/4)+idx4];
      s.x+=t2.x; s.y+=t2.y; s.z+=t2.z; s.w+=t2.w;
    }
    const float4 b4 = ((const float4*)bias)[idx4 & 255];
    s.x+=b4.x; s.y+=b4.y; s.z+=b4.z; s.w+=b4.w;
    if (relu) { s.x=fmaxf(s.x,0.f); s.y=fmaxf(s.y,0.f);
                s.z=fmaxf(s.z,0.f); s.w=fmaxf(s.w,0.f); }
    if (extra) {
      const float4 e = ((const float4*)extra)[idx4];
      s.x+=e.x; s.y+=e.y; s.z+=e.z; s.w+=e.w;
    }
    ((float4*)out)[idx4] = s;
  } else {
    const int gw = (bid-128)*4 + wave;    // 0..3583
    attn_range<true,false>(p, wbase + gw*2, wbase + gw*2 + 2, lane);
  }
}

// mopup: 4096 waves cover remaining 25600 rows (1024 x 7, 3072 x 6)
__global__ __launch_bounds__(256,4) void mopup(Params p)
{
  const int gw = blockIdx.x*4 + (threadIdx.x>>6);
  const int lane = threadIdx.x & 63;
  int r0, n;
  if (gw < 1024) { r0 = MBASE + gw*7;             n = 7; }
  else           { r0 = MBASE + 7168 + (gw-1024)*6; n = 6; }
  attn_range<true,false>(p, r0, r0 + n, lane);
}

// ---------------------------------------------------------------------------
extern "C" void kernel_launch(void* const* d_in, const int* in_sizes, int n_in,
                              void* d_out, int out_size, void* d_ws, size_t ws_size,
                              hipStream_t stream)
{
  (void)in_sizes; (void)n_in; (void)out_size; (void)ws_size;
  Params p;
  p.x  = (const float*)d_in[0];
  p.Wq = (const float*)d_in[1];  p.bq = (const float*)d_in[2];
  p.Wk = (const float*)d_in[3];  p.bk = (const float*)d_in[4];
  p.Wv = (const float*)d_in[5];  p.bv = (const float*)d_in[6];
  p.Wo = (const float*)d_in[7];  p.bo = (const float*)d_in[8];
  p.W1 = (const float*)d_in[9];  p.b1 = (const float*)d_in[10];
  p.W2 = (const float*)d_in[11]; p.b2 = (const float*)d_in[12];
  p.out = (float*)d_out;
  p.nw  = p.out + MAT;
  float* ws = (float*)d_ws;
  p.q    = ws;         p.k  = ws + MAT;   p.v = ws + 2*MAT;
  p.araw = ws + 3*MAT; p.x2 = ws + 4*MAT; p.h = ws + 5*MAT;
  p.P    = ws + 6*MAT;

  qkv_partial<<<dim3(16,8,3), 256, 0, stream>>>(p.x, p.Wq, p.Wk, p.Wv, p.P);
  qkv_reduce<<<384, 256, 0, stream>>>(p);

  attn_mixed<<<1024, 256, 0, stream>>>(p);

  chainA<<<1024, 256, 0, stream>>>(p, p.araw, p.Wo, A_WO);
  chainB<<<1024, 256, 0, stream>>>(p, p.bo, p.x, p.x2, 0, B_WO);

  chainA<<<1024, 256, 0, stream>>>(p, p.x2, p.W1, A_W1);
  chainB<<<1024, 256, 0, stream>>>(p, p.b1, nullptr, p.h, 1, B_W1);

  chainA<<<1024, 256, 0, stream>>>(p, p.h, p.W2, A_W2);
  chainB<<<1024, 256, 0, stream>>>(p, p.b2, p.x2, p.out, 0, B_W2);

  mopup<<<1024, 256, 0, stream>>>(p);
}